// Round 16
// baseline (158.910 us; speedup 1.0000x reference)
//
#include <hip/hip_runtime.h>

typedef unsigned short u16;
typedef unsigned int u32;
typedef __attribute__((ext_vector_type(8))) short bf16x8;
typedef __attribute__((ext_vector_type(8))) _Float16 f16x8;
typedef __attribute__((ext_vector_type(4))) float f32x4;

__device__ inline u16 f2bf(float f){
  union { float f; unsigned u; } v; v.f = f;
  unsigned r = v.u + 0x7FFFu + ((v.u >> 16) & 1u);
  return (u16)(r >> 16);
}
__device__ inline float bf2f(u16 u){
  union { unsigned u; float f; } v; v.u = ((unsigned)u) << 16;
  return v.f;
}
__device__ inline u16 f2h(float f){
  union { _Float16 h; u16 u; } v; v.h = (_Float16)f; return v.u;
}

// async 16B/lane global->LDS. lds dest is wave-uniform base + lane*16 (HW).
__device__ inline void gload16(const u16* g, u16* l){
  __builtin_amdgcn_global_load_lds(
      (const __attribute__((address_space(1))) u32*)(const void*)g,
      (__attribute__((address_space(3))) u32*)(void*)l, 16, 0, 0);
}

#define WAITV(n) asm volatile("s_waitcnt vmcnt(" #n ")" ::: "memory")
#define FENCE()  asm volatile("" ::: "memory")
#define BARR     __builtin_amdgcn_s_barrier()
#define MSYNC    do{ asm volatile("s_waitcnt lgkmcnt(0)" ::: "memory"); \
                     __builtin_amdgcn_sched_barrier(0); }while(0)

// ---------------- prep: split Wq+Wk fp32 -> bf16 hi/lo (one launch) --------
__global__ __launch_bounds__(256) void split_wqk(const float* __restrict__ wq,
                                                 const float* __restrict__ wk,
                                                 u16* __restrict__ qh, u16* __restrict__ ql,
                                                 u16* __restrict__ kh, u16* __restrict__ kl){
  int b = blockIdx.x;
  const float* x; u16 *hi, *lo;
  int i;
  if (b < 1024){ x = wq; hi = qh; lo = ql; i = b * 256 + threadIdx.x; }
  else         { x = wk; hi = kh; lo = kl; i = (b - 1024) * 256 + threadIdx.x; }
  float4 v = ((const float4*)x)[i];
  float a0 = v.x, a1 = v.y, a2 = v.z, a3 = v.w;
  u16 h0 = f2bf(a0), h1 = f2bf(a1), h2 = f2bf(a2), h3 = f2bf(a3);
  ushort4 h; h.x = h0; h.y = h1; h.z = h2; h.w = h3;
  ushort4 l; l.x = f2bf(a0 - bf2f(h0)); l.y = f2bf(a1 - bf2f(h1));
  l.z = f2bf(a2 - bf2f(h2)); l.w = f2bf(a3 - bf2f(h3));
  ((ushort4*)hi)[i] = h;
  ((ushort4*)lo)[i] = l;
}

// ---------------- prep: z -> fp16 copy ----------------
__global__ __launch_bounds__(256) void conv_h16(const float* __restrict__ x,
                                                u16* __restrict__ h16, int n4){
  int i = blockIdx.x * 256 + threadIdx.x;
  if (i >= n4) return;
  float4 v = ((const float4*)x)[i];
  ushort4 g; g.x = f2h(v.x); g.y = f2h(v.y); g.z = f2h(v.z); g.w = f2h(v.w);
  ((ushort4*)h16)[i] = g;
}

// ---------------- prep: transpose Wv -> fp16 ----------------
__global__ __launch_bounds__(256) void transpose_wv16(
    const float* __restrict__ W, u16* __restrict__ H){
  __shared__ float t[64][65];
  int d0 = blockIdx.y * 64, n0 = blockIdx.x * 64;
  int tid = threadIdx.x;
  int r = tid >> 4, c4 = (tid & 15) * 4;
  for (int rr = r; rr < 64; rr += 16){
    float4 v = *(const float4*)&W[(size_t)(d0 + rr) * 1024 + n0 + c4];
    t[rr][c4 + 0] = v.x; t[rr][c4 + 1] = v.y; t[rr][c4 + 2] = v.z; t[rr][c4 + 3] = v.w;
  }
  __syncthreads();
  int n = tid >> 4, d4 = (tid & 15) * 4;
  for (int nn = n; nn < 64; nn += 16){
    ushort4 h;
    h.x = f2h(t[d4 + 0][nn]); h.y = f2h(t[d4 + 1][nn]);
    h.z = f2h(t[d4 + 2][nn]); h.w = f2h(t[d4 + 3][nn]);
    *(ushort4*)&H[(size_t)(n0 + nn) * 1024 + d0 + d4] = h;
  }
}

// ---------------- small GEMM (128x128 tile, 4 waves): m' only --------------
template<int IN, int EPI>
__global__ __launch_bounds__(256) void gemm_bt(
    const u16* __restrict__ Ah, const u16* __restrict__ Al, int lda,
    const u16* __restrict__ Bh, const u16* __restrict__ Bl, int ldb,
    void* __restrict__ C0, int ldc, int K, size_t zslab){
  constexpr int NPL = 4;
  constexpr int DEPTH = 1;
  constexpr int NBUF = DEPTH + 1;
  __shared__ __align__(16) u16 sm[NBUF * NPL * 4096];

  const int kz = blockIdx.z * K;
  Ah += kz; Bh += kz; Al += kz; Bl += kz;

  const int tid = threadIdx.x;
  const int lane = tid & 63, wave = tid >> 6;
  const int wr = wave >> 1, wc = wave & 1;
  const int lr = lane & 15, kg = lane >> 4;

  const int nwg = gridDim.x * gridDim.y;
  const int id = blockIdx.y * gridDim.x + blockIdx.x;
  const int chunk = nwg >> 3;
  const int swz = (id & 7) * chunk + (id >> 3);
  const int bx = swz % gridDim.x, by = swz / gridDim.x;
  const int m0 = by * 128, n0 = bx * 128;

  const int l_r = lane >> 2, l_c = lane & 3;
  const int st_chunk = l_c ^ ((l_r + (l_r >> 2)) & 3);
  const int rd_swz = (lr + (lr >> 2)) & 3;

  f32x4 acc[4][4];
  #pragma unroll
  for (int m = 0; m < 4; m++)
    #pragma unroll
    for (int n = 0; n < 4; n++)
      acc[m][n] = (f32x4){0.f, 0.f, 0.f, 0.f};

  auto STAGE = [&](int buf, int k0){
    #pragma unroll
    for (int c = 0; c < NPL * 2; ++c){
      int pc = c * 4 + wave;
      int p = pc >> 3, ch = pc & 7;
      const u16* g = (p == 0) ? Ah : (p == 1) ? Al : (p == 2) ? Bh : Bl;
      int ld = (p < 2) ? lda : ldb;
      int rb = (p < 2) ? m0 : n0;
      int r = ch * 16 + l_r;
      const u16* src = g + (size_t)(rb + r) * ld + k0 + st_chunk * 8;
      u16* dst = &sm[((size_t)buf * NPL + p) * 4096 + ch * 512];
      gload16(src, dst);
    }
  };

  const int KT = K >> 5;
  STAGE(0, 0);

  int bufc = 0, pfb = DEPTH % NBUF;
  for (int kt = 0; kt < KT; ++kt){
    const int pf = kt + DEPTH;
    if (pf < KT){
      STAGE(pfb, pf * 32);
      WAITV(8);
    } else {
      WAITV(0);
    }
    BARR;
    FENCE();

    const u16* pA  = &sm[((size_t)bufc * NPL + 0) * 4096];
    const u16* pAl = &sm[((size_t)bufc * NPL + 1) * 4096];
    const u16* pB  = &sm[((size_t)bufc * NPL + 2) * 4096];
    const u16* pBl = &sm[((size_t)bufc * NPL + 3) * 4096];

    const int slot = (kg ^ rd_swz) * 8;
    bf16x8 afh[4], bfh[4], afl[4], bfl[4];
    #pragma unroll
    for (int m = 0; m < 4; m++){
      int r = wr * 64 + m * 16 + lr;
      afh[m] = *(const bf16x8*)&pA[r * 32 + slot];
      afl[m] = *(const bf16x8*)&pAl[r * 32 + slot];
    }
    #pragma unroll
    for (int n = 0; n < 4; n++){
      int r = wc * 64 + n * 16 + lr;
      bfh[n] = *(const bf16x8*)&pB[r * 32 + slot];
      bfl[n] = *(const bf16x8*)&pBl[r * 32 + slot];
    }
    #pragma unroll
    for (int m = 0; m < 4; m++)
      #pragma unroll
      for (int n = 0; n < 4; n++){
        acc[m][n] = __builtin_amdgcn_mfma_f32_16x16x32_bf16(afh[m], bfh[n], acc[m][n], 0, 0, 0);
        acc[m][n] = __builtin_amdgcn_mfma_f32_16x16x32_bf16(afl[m], bfh[n], acc[m][n], 0, 0, 0);
        acc[m][n] = __builtin_amdgcn_mfma_f32_16x16x32_bf16(afh[m], bfl[n], acc[m][n], 0, 0, 0);
      }
    FENCE();
    BARR;
    bufc = (bufc + 1 == NBUF) ? 0 : bufc + 1;
    pfb  = (pfb  + 1 == NBUF) ? 0 : pfb  + 1;
  }

  const int row0 = m0 + wr * 64, col0 = n0 + wc * 64 + lr;
  float* C = (float*)C0 + (size_t)blockIdx.z * zslab;
  #pragma unroll
  for (int m = 0; m < 4; m++)
    #pragma unroll
    for (int n = 0; n < 4; n++)
      #pragma unroll
      for (int r = 0; r < 4; r++){
        int row = row0 + m * 16 + kg * 4 + r;
        int col = col0 + n * 16;
        C[(size_t)row * ldc + col] = acc[m][n][r];
      }
}

// ---------------- dual GEMM: t (z@m'^T) || v^T (Wv^T@z^T) in one launch ----
__global__ __launch_bounds__(256) void gemm_dual(
    const u16* __restrict__ A0, int lda0, const u16* __restrict__ B0, int ldb0,
    u16* __restrict__ C0_, int ldc0, int gx0,
    const u16* __restrict__ A1, int lda1, const u16* __restrict__ B1, int ldb1,
    u16* __restrict__ C1_, int ldc1, int gx1, int K){
  constexpr int NPL = 2, DEPTH = 2, NBUF = 3;
  __shared__ __align__(16) u16 sm[NBUF * NPL * 4096];

  const int id = blockIdx.x;
  const int l = id & 255;
  const int swz = (l & 7) * 32 + (l >> 3);
  const u16* Ah; const u16* Bh; u16* C; int lda, ldb, ldc, gx;
  if (id < 256){ Ah = A0; Bh = B0; C = C0_; lda = lda0; ldb = ldb0; ldc = ldc0; gx = gx0; }
  else         { Ah = A1; Bh = B1; C = C1_; lda = lda1; ldb = ldb1; ldc = ldc1; gx = gx1; }
  const int bx = swz % gx, by = swz / gx;
  const int m0 = by * 128, n0 = bx * 128;

  const int tid = threadIdx.x;
  const int lane = tid & 63, wave = tid >> 6;
  const int wr = wave >> 1, wc = wave & 1;
  const int lr = lane & 15, kg = lane >> 4;
  const int l_r = lane >> 2, l_c = lane & 3;
  const int st_chunk = l_c ^ ((l_r + (l_r >> 2)) & 3);
  const int rd_swz = (lr + (lr >> 2)) & 3;

  f32x4 acc[4][4];
  #pragma unroll
  for (int m = 0; m < 4; m++)
    #pragma unroll
    for (int n = 0; n < 4; n++)
      acc[m][n] = (f32x4){0.f, 0.f, 0.f, 0.f};

  auto STAGE = [&](int buf, int k0){
    #pragma unroll
    for (int c = 0; c < NPL * 2; ++c){
      int pc = c * 4 + wave;
      int p = pc >> 3, ch = pc & 7;
      const u16* g = (p == 0) ? Ah : Bh;
      int ld = (p == 0) ? lda : ldb;
      int rb = (p == 0) ? m0 : n0;
      int r = ch * 16 + l_r;
      const u16* src = g + (size_t)(rb + r) * ld + k0 + st_chunk * 8;
      u16* dst = &sm[((size_t)buf * NPL + p) * 4096 + ch * 512];
      gload16(src, dst);
    }
  };

  const int KT = K >> 5;
  STAGE(0, 0);
  if (KT > 1) STAGE(1, 32);

  int bufc = 0, pfb = DEPTH % NBUF;
  for (int kt = 0; kt < KT; ++kt){
    const int pf = kt + DEPTH;
    if (pf < KT){
      STAGE(pfb, pf * 32);
      WAITV(8);
    } else if (kt + 1 < KT){
      WAITV(4);
    } else {
      WAITV(0);
    }
    BARR;
    FENCE();

    const u16* pA = &sm[((size_t)bufc * NPL + 0) * 4096];
    const u16* pB = &sm[((size_t)bufc * NPL + 1) * 4096];

    const int slot = (kg ^ rd_swz) * 8;
    f16x8 ah[4], bh[4];
    #pragma unroll
    for (int m = 0; m < 4; m++){
      int r = wr * 64 + m * 16 + lr;
      ah[m] = *(const f16x8*)&pA[r * 32 + slot];
    }
    #pragma unroll
    for (int n = 0; n < 4; n++){
      int r = wc * 64 + n * 16 + lr;
      bh[n] = *(const f16x8*)&pB[r * 32 + slot];
    }
    #pragma unroll
    for (int m = 0; m < 4; m++)
      #pragma unroll
      for (int n = 0; n < 4; n++)
        acc[m][n] = __builtin_amdgcn_mfma_f32_16x16x32_f16(ah[m], bh[n], acc[m][n], 0, 0, 0);
    FENCE();
    BARR;
    bufc = (bufc + 1 == NBUF) ? 0 : bufc + 1;
    pfb  = (pfb  + 1 == NBUF) ? 0 : pfb  + 1;
  }

  const int row0 = m0 + wr * 64, col0 = n0 + wc * 64 + lr;
  #pragma unroll
  for (int m = 0; m < 4; m++)
    #pragma unroll
    for (int n = 0; n < 4; n++)
      #pragma unroll
      for (int r = 0; r < 4; r++){
        int row = row0 + m * 16 + kg * 4 + r;
        int col = col0 + n * 16;
        C[(size_t)row * ldc + col] = f2h(acc[m][n][r]);
      }
}

// ---------------- big GEMM: 256x256, BK=64, faithful 8-phase (T3+T4+T5) ----
// fp16 in. EPI 0 = fp32 out; 1 = fp16 out.
// LDS = 128KB: per operand 2buf x 2half x 16KB. Halves are QUADRANT-halves:
//   A-half h = global rows { wr*128 + h*64 + [0,64) } for wr in {0,1}
//   B-half h = global rows { wc*64 + h*32 + [0,32) } for wc in {0,4}
// Phases per iteration (tiles T=2j -> buf0, T+1 -> buf1), quadrant order
// Q(0,0) Q(0,1) Q(1,0) Q(1,1) per tile; B-fragments held in regs (b0,b1):
//  ph1: rd A0h0(8)+B0h0(4); stage Ah1(T+1)->b1   MFMA Q(0,0)
//  ph2: rd B0h1(4);         stage Ah0(T+2)->b0   MFMA Q(0,1)
//  ph3: rd A0h1(8);         stage Bh0(T+2)->b0   MFMA Q(1,0)
//  ph4: -;                  stage Bh1(T+2)->b0 + vmcnt(6)   MFMA Q(1,1)
//  ph5-8: same for tile T+1 (buf1), staging T+2's Ah1 then T+3's halves,
//         vmcnt(6) at ph8.
// Ledger verified: every stage targets a slot freed >=1 barrier earlier;
// every read is covered by a prior vmcnt(6)+barrier (3 halves = 6 loads max
// in flight). Tail: stages guarded by s2, waits drop to vmcnt(0). KT even.
template<int EPI>
__global__ __launch_bounds__(512, 1) void gemm256p(
    const u16* __restrict__ A, int lda,
    const u16* __restrict__ B, int ldb,
    void* __restrict__ C0z, int l0, void* __restrict__ C1z, int l1,
    void* __restrict__ C2z, int l2, void* __restrict__ C3z, int l3,
    int K){
  __shared__ __align__(16) u16 sm[8 * 8192];   // [(op*2+buf)*2+half] 16KB halves

  const int tid = threadIdx.x;
  const int lane = tid & 63, wave = tid >> 6;
  const int wr = wave >> 2, wc = wave & 3;        // 2M x 4N waves
  const int lr = lane & 15, kg = lane >> 4;

  const int nwg = gridDim.x * gridDim.y;
  const int id = blockIdx.y * gridDim.x + blockIdx.x;
  const int chunk = nwg >> 3;
  const int swz = (id & 7) * chunk + (id >> 3);
  const int bx = swz % gridDim.x, by = swz / gridDim.x;
  const int m0 = by * 256, n0 = bx * 256;

  A += (size_t)blockIdx.z * (size_t)K;
  B += (size_t)blockIdx.z * (size_t)K;
  void* Cp; int ldc;
  if (blockIdx.z == 0){ Cp = C0z; ldc = l0; }
  else if (blockIdx.z == 1){ Cp = C1z; ldc = l1; }
  else if (blockIdx.z == 2){ Cp = C2z; ldc = l2; }
  else { Cp = C3z; ldc = l3; }

  // stage one 16KB half (2 gload16/thread, linear dest, pre-swizzled source)
  auto SH = [&](int op, int buf, int half, int k0){
    u16* base = &sm[(size_t)((op * 2 + buf) * 2 + half) * 8192];
    const u16* g = op ? B : A;
    const int ld = op ? ldb : lda;
    const int rb = op ? n0 : m0;
    #pragma unroll
    for (int rd = 0; rd < 2; ++rd){
      int ri = rd * 64 + wave * 8 + (lane >> 3);
      int r  = op ? ((ri >> 5) * 64 + half * 32 + (ri & 31))
                  : ((ri >> 6) * 128 + half * 64 + (ri & 63));
      int gch = (lane & 7) ^ (ri & 7);
      gload16(g + (size_t)(rb + r) * ld + k0 + gch * 8,
              base + ri * 64 + (lane & 7) * 8);
    }
  };

  const u16* pA0h0 = sm + 0 * 8192;  const u16* pA0h1 = sm + 1 * 8192;
  const u16* pA1h0 = sm + 2 * 8192;  const u16* pA1h1 = sm + 3 * 8192;
  const u16* pB0h0 = sm + 4 * 8192;  const u16* pB0h1 = sm + 5 * 8192;
  const u16* pB1h0 = sm + 6 * 8192;  const u16* pB1h1 = sm + 7 * 8192;

  auto RA = [&](const u16* h, int m, int ks) -> f16x8 {
    int ri = wr * 64 + m * 16 + lr;
    return *(const f16x8*)&h[ri * 64 + (((ks * 4 + kg) ^ (ri & 7)) * 8)];
  };
  auto RB = [&](const u16* h, int n, int ks) -> f16x8 {
    int ri = wc * 32 + n * 16 + lr;
    return *(const f16x8*)&h[ri * 64 + (((ks * 4 + kg) ^ (ri & 7)) * 8)];
  };

  f32x4 acc[8][4];
  #pragma unroll
  for (int m = 0; m < 8; m++)
    #pragma unroll
    for (int n = 0; n < 4; n++)
      acc[m][n] = (f32x4){0.f, 0.f, 0.f, 0.f};

  f16x8 a[4][2], b0[2][2], b1[2][2];

#define RDA(H) do{ _Pragma("unroll") \
    for (int m_ = 0; m_ < 4; m_++){ a[m_][0] = RA(H, m_, 0); a[m_][1] = RA(H, m_, 1); } }while(0)
#define RDB(DST, H) do{ _Pragma("unroll") \
    for (int n_ = 0; n_ < 2; n_++){ DST[n_][0] = RB(H, n_, 0); DST[n_][1] = RB(H, n_, 1); } }while(0)
#define MMQ(QM, QN, BB) do{ \
    __builtin_amdgcn_s_setprio(1); \
    _Pragma("unroll") \
    for (int m_ = 0; m_ < 4; m_++){ \
      _Pragma("unroll") \
      for (int n_ = 0; n_ < 2; n_++){ \
        acc[QM*4+m_][QN*2+n_] = __builtin_amdgcn_mfma_f32_16x16x32_f16(a[m_][0], BB[n_][0], acc[QM*4+m_][QN*2+n_], 0, 0, 0); \
        acc[QM*4+m_][QN*2+n_] = __builtin_amdgcn_mfma_f32_16x16x32_f16(a[m_][1], BB[n_][1], acc[QM*4+m_][QN*2+n_], 0, 0, 0); \
      } } \
    __builtin_amdgcn_s_setprio(0); }while(0)

  const int KT = K >> 6;                 // 16 here (even, >=2)
  // prologue: tile0 all 4 halves (buf0), tile1 Ah0,Bh0,Bh1 (buf1)
  SH(0, 0, 0, 0); SH(0, 0, 1, 0); SH(1, 0, 0, 0); SH(1, 0, 1, 0);
  SH(0, 1, 0, 64); SH(1, 1, 0, 64); SH(1, 1, 1, 64);
  WAITV(6);                              // tile0's 8 loads retired
  BARR;

  for (int j = 0; j < (KT >> 1); ++j){
    const int T = 2 * j;
    const bool s2 = (T + 2) < KT;
    const int k1 = (T + 1) * 64, k2 = (T + 2) * 64, k3 = (T + 3) * 64;

    // ph1: Q(0,0) of T
    RDA(pA0h0); RDB(b0, pB0h0);
    SH(0, 1, 1, k1);                     // Ah1(T+1) -> buf1 (freed prev ph7)
    BARR; MSYNC; MMQ(0, 0, b0); BARR;
    // ph2: Q(0,1) of T
    RDB(b1, pB0h1);
    if (s2) SH(0, 0, 0, k2);             // Ah0(T+2) (freed ph1)
    BARR; MSYNC; MMQ(0, 1, b1); BARR;
    // ph3: Q(1,0) of T
    RDA(pA0h1);
    if (s2) SH(1, 0, 0, k2);             // Bh0(T+2) (freed ph1)
    BARR; MSYNC; MMQ(1, 0, b0); BARR;
    // ph4: Q(1,1) of T
    if (s2){ SH(1, 0, 1, k2); WAITV(6); } else { WAITV(0); }
    BARR; MSYNC; MMQ(1, 1, b1); BARR;
    // ph5: Q(0,0) of T+1
    RDA(pA1h0); RDB(b0, pB1h0);
    if (s2) SH(0, 0, 1, k2);             // Ah1(T+2) (freed ph3)
    BARR; MSYNC; MMQ(0, 0, b0); BARR;
    // ph6: Q(0,1) of T+1
    RDB(b1, pB1h1);
    if (s2) SH(0, 1, 0, k3);             // Ah0(T+3) (freed ph5)
    BARR; MSYNC; MMQ(0, 1, b1); BARR;
    // ph7: Q(1,0) of T+1
    RDA(pA1h1);
    if (s2) SH(1, 1, 0, k3);             // Bh0(T+3) (freed ph5)
    BARR; MSYNC; MMQ(1, 0, b0); BARR;
    // ph8: Q(1,1) of T+1
    if (s2){ SH(1, 1, 1, k3); WAITV(6); } else { WAITV(0); }
    BARR; MSYNC; MMQ(1, 1, b1); BARR;
  }
#undef RDA
#undef RDB
#undef MMQ

  const int row0 = m0 + wr * 128, col0 = n0 + wc * 64 + lr;
  #pragma unroll
  for (int m = 0; m < 8; m++)
    #pragma unroll
    for (int n = 0; n < 4; n++)
      #pragma unroll
      for (int r = 0; r < 4; r++){
        int row = row0 + m * 16 + kg * 4 + r;
        int col = col0 + n * 16;
        if (EPI == 0) ((float*)Cp)[(size_t)row * ldc + col] = acc[m][n][r];
        else          ((u16*)Cp)[(size_t)row * ldc + col] = f2h(acc[m][n][r]);
      }
}

// ---------------- reduce: dst16 = fp16(s0+s1+s2+s3) ----------------
__global__ __launch_bounds__(256) void reduce_t(u16* __restrict__ dst,
                                                const float* __restrict__ s0,
                                                const float* __restrict__ s1,
                                                const float* __restrict__ s2,
                                                const float* __restrict__ s3){
  int idx = blockIdx.x * 256 + threadIdx.x;
  float4 a = ((const float4*)s0)[idx];
  float4 b = ((const float4*)s1)[idx];
  float4 c = ((const float4*)s2)[idx];
  float4 d = ((const float4*)s3)[idx];
  ushort4 o;
  o.x = f2h((a.x + b.x) + (c.x + d.x));
  o.y = f2h((a.y + b.y) + (c.y + d.y));
  o.z = f2h((a.z + b.z) + (c.z + d.z));
  o.w = f2h((a.w + b.w) + (c.w + d.w));
  ((ushort4*)dst)[idx] = o;
}

// ---------------- reduce: out += s1 + s2 + s3 (flat fp32 slabs) ------------
__global__ __launch_bounds__(256) void reduce_pv4(float* __restrict__ out,
                                                  const float* __restrict__ s1,
                                                  const float* __restrict__ s2,
                                                  const float* __restrict__ s3){
  int idx = blockIdx.x * 256 + threadIdx.x;
  float4 a = ((const float4*)out)[idx];
  float4 b = ((const float4*)s1)[idx];
  float4 c = ((const float4*)s2)[idx];
  float4 d = ((const float4*)s3)[idx];
  float4 o;
  o.x = (a.x + b.x) + (c.x + d.x);
  o.y = (a.y + b.y) + (c.y + d.y);
  o.z = (a.z + b.z) + (c.z + d.z);
  o.w = (a.w + b.w) + (c.w + d.w);
  ((float4*)out)[idx] = o;
}

// ---------------- softmax over fp16 S rows (4096), write P fp16 in place ---
__global__ __launch_bounds__(256) void softmax16(u16* __restrict__ S){
  int row = blockIdx.x;
  _Float16* srow = (_Float16*)(S + (size_t)row * 4096);
  __shared__ float e[4096];
  __shared__ float red[4];
  int tid = threadIdx.x;

  float m = -1e30f;
  for (int i = tid * 8; i < 4096; i += 2048){
    f16x8 v = *(const f16x8*)(srow + i);
    #pragma unroll
    for (int j = 0; j < 8; j++) m = fmaxf(m, (float)v[j]);
  }
  for (int o = 32; o > 0; o >>= 1) m = fmaxf(m, __shfl_xor(m, o));
  if ((tid & 63) == 0) red[tid >> 6] = m;
  __syncthreads();
  m = fmaxf(fmaxf(red[0], red[1]), fmaxf(red[2], red[3]));

  float s = 0.f;
  for (int i = tid * 8; i < 4096; i += 2048){
    f16x8 v = *(const f16x8*)(srow + i);
    #pragma unroll
    for (int j = 0; j < 8; j++){
      float ev = __expf((float)v[j] - m);
      s += ev;
      e[i + j] = ev;
    }
  }
  for (int o = 32; o > 0; o >>= 1) s += __shfl_xor(s, o);
  __syncthreads();
  if ((tid & 63) == 0) red[tid >> 6] = s;
  __syncthreads();
  s = (red[0] + red[1]) + (red[2] + red[3]);

  float scale = 0.03125f / s;    // fold post-softmax 1/sqrt(dk)=1/32 into P
  for (int i = tid * 8; i < 4096; i += 2048){
    f16x8 o;
    #pragma unroll
    for (int j = 0; j < 8; j++) o[j] = (_Float16)(e[i + j] * scale);
    *(f16x8*)(srow + i) = o;
  }
}

extern "C" void kernel_launch(void* const* d_in, const int* in_sizes, int n_in,
                              void* d_out, int out_size, void* d_ws, size_t ws_size,
                              hipStream_t stream){
  const float* z  = (const float*)d_in[0];
  const float* Wq = (const float*)d_in[1];
  const float* Wk = (const float*)d_in[2];
  const float* Wv = (const float*)d_in[3];
  char* ws = (char*)d_ws;
  const size_t MB = 1ull << 20;

  // layout: 0-8 t16 | 8-16 z16 | 16-24 vt16 | 24-56 S/P fp16 | 56-88 PV slabs
  //         88-90 m16. prep scratch 24-56 (dead before S written).
  u16* t16   = (u16*)(ws + 0 * MB);
  u16* z16   = (u16*)(ws + 8 * MB);
  u16* vt16  = (u16*)(ws + 16 * MB);
  u16* S16   = (u16*)(ws + 24 * MB);              // fp16 [4096][4096]
  u16* m16   = (u16*)(ws + 88 * MB);
  float* pv1 = (float*)(ws + 56 * MB);            // PV partial slabs
  float* pv2 = (float*)(ws + 72 * MB);
  float* pv3 = (float*)(ws + 0 * MB);             // t16/z16 dead after S
  // prep scratch (24-56, dead before S):
  u16* wqh   = (u16*)(ws + 24 * MB);
  u16* wql   = (u16*)(ws + 26 * MB);
  u16* wkh   = (u16*)(ws + 28 * MB);
  u16* wkl   = (u16*)(ws + 30 * MB);
  u16* wvt16 = (u16*)(ws + 32 * MB);
  float* msl = (float*)(ws + 40 * MB);            // m' slabs 4x4MB (40-56)

  conv_h16<<<4096, 256, 0, stream>>>(z, z16, 4096 * 1024 / 4);
  split_wqk<<<2048, 256, 0, stream>>>(Wq, Wk, wqh, wql, wkh, wkl);
  transpose_wv16<<<dim3(16, 16), 256, 0, stream>>>(Wv, wvt16);

  // m'[m,n] = sum_a Wk[m,a] Wq[n,a]  (split, split-K=4 -> fp32 slabs)
  gemm_bt<0, 0><<<dim3(8, 8, 4), 256, 0, stream>>>(wkh, wkl, 1024,
      wqh, wql, 1024, msl, 1024, 256, (size_t)1024 * 1024);
  reduce_t<<<1024, 256, 0, stream>>>(m16, msl, msl + 1048576,
      msl + 2097152, msl + 3145728);

  // t = z16 @ m16^T  ||  v^T = Wv^T @ z^T   (one 512-block launch)
  gemm_dual<<<512, 256, 0, stream>>>(
      z16, 1024, m16, 1024, t16, 1024, 8,
      wvt16, 1024, z16, 1024, vt16, 4096, 32, 1024);

  // S = t16 @ z16^T  fp16 out  M=N=4096 K=1024 (8-phase kernel)
  gemm256p<1><<<dim3(16, 16, 1), 512, 0, stream>>>(t16, 1024, z16, 1024,
      S16, 4096, S16, 4096, S16, 4096, S16, 4096, 1024);

  // softmax rows (fp16 in/out, in place), 1/32 folded in
  softmax16<<<4096, 256, 0, stream>>>(S16);

  // out = P @ v, split-K=4: z0 -> d_out, z1-3 -> flat fp32 slabs
  gemm256p<0><<<dim3(4, 16, 4), 512, 0, stream>>>(S16, 4096, vt16, 4096,
      (float*)d_out, 1024, pv1, 1024, pv2, 1024, pv3, 1024, 1024);

  // out += pv1 + pv2 + pv3
  reduce_pv4<<<4096, 256, 0, stream>>>((float*)d_out, pv1, pv2, pv3);
}

// Round 17
// 158.429 us; speedup vs baseline: 1.0030x; 1.0030x over previous
//
#include <hip/hip_runtime.h>

typedef unsigned short u16;
typedef unsigned int u32;
typedef __attribute__((ext_vector_type(8))) short bf16x8;
typedef __attribute__((ext_vector_type(8))) _Float16 f16x8;
typedef __attribute__((ext_vector_type(4))) float f32x4;

__device__ inline u16 f2bf(float f){
  union { float f; unsigned u; } v; v.f = f;
  unsigned r = v.u + 0x7FFFu + ((v.u >> 16) & 1u);
  return (u16)(r >> 16);
}
__device__ inline float bf2f(u16 u){
  union { unsigned u; float f; } v; v.u = ((unsigned)u) << 16;
  return v.f;
}
__device__ inline u16 f2h(float f){
  union { _Float16 h; u16 u; } v; v.h = (_Float16)f; return v.u;
}

// async 16B/lane global->LDS. lds dest is wave-uniform base + lane*16 (HW).
__device__ inline void gload16(const u16* g, u16* l){
  __builtin_amdgcn_global_load_lds(
      (const __attribute__((address_space(1))) u32*)(const void*)g,
      (__attribute__((address_space(3))) u32*)(void*)l, 16, 0, 0);
}

#define WAITV(n) asm volatile("s_waitcnt vmcnt(" #n ")" ::: "memory")
#define FENCE()  asm volatile("" ::: "memory")

// ---------------- prep: split Wq+Wk fp32 -> bf16 hi/lo (one launch) --------
__global__ __launch_bounds__(256) void split_wqk(const float* __restrict__ wq,
                                                 const float* __restrict__ wk,
                                                 u16* __restrict__ qh, u16* __restrict__ ql,
                                                 u16* __restrict__ kh, u16* __restrict__ kl){
  int b = blockIdx.x;
  const float* x; u16 *hi, *lo;
  int i;
  if (b < 1024){ x = wq; hi = qh; lo = ql; i = b * 256 + threadIdx.x; }
  else         { x = wk; hi = kh; lo = kl; i = (b - 1024) * 256 + threadIdx.x; }
  float4 v = ((const float4*)x)[i];
  float a0 = v.x, a1 = v.y, a2 = v.z, a3 = v.w;
  u16 h0 = f2bf(a0), h1 = f2bf(a1), h2 = f2bf(a2), h3 = f2bf(a3);
  ushort4 h; h.x = h0; h.y = h1; h.z = h2; h.w = h3;
  ushort4 l; l.x = f2bf(a0 - bf2f(h0)); l.y = f2bf(a1 - bf2f(h1));
  l.z = f2bf(a2 - bf2f(h2)); l.w = f2bf(a3 - bf2f(h3));
  ((ushort4*)hi)[i] = h;
  ((ushort4*)lo)[i] = l;
}

// ---------------- prep: z -> fp16 copy ----------------
__global__ __launch_bounds__(256) void conv_h16(const float* __restrict__ x,
                                                u16* __restrict__ h16, int n4){
  int i = blockIdx.x * 256 + threadIdx.x;
  if (i >= n4) return;
  float4 v = ((const float4*)x)[i];
  ushort4 g; g.x = f2h(v.x); g.y = f2h(v.y); g.z = f2h(v.z); g.w = f2h(v.w);
  ((ushort4*)h16)[i] = g;
}

// ---------------- prep: transpose Wv -> fp16 ----------------
__global__ __launch_bounds__(256) void transpose_wv16(
    const float* __restrict__ W, u16* __restrict__ H){
  __shared__ float t[64][65];
  int d0 = blockIdx.y * 64, n0 = blockIdx.x * 64;
  int tid = threadIdx.x;
  int r = tid >> 4, c4 = (tid & 15) * 4;
  for (int rr = r; rr < 64; rr += 16){
    float4 v = *(const float4*)&W[(size_t)(d0 + rr) * 1024 + n0 + c4];
    t[rr][c4 + 0] = v.x; t[rr][c4 + 1] = v.y; t[rr][c4 + 2] = v.z; t[rr][c4 + 3] = v.w;
  }
  __syncthreads();
  int n = tid >> 4, d4 = (tid & 15) * 4;
  for (int nn = n; nn < 64; nn += 16){
    ushort4 h;
    h.x = f2h(t[d4 + 0][nn]); h.y = f2h(t[d4 + 1][nn]);
    h.z = f2h(t[d4 + 2][nn]); h.w = f2h(t[d4 + 3][nn]);
    *(ushort4*)&H[(size_t)(n0 + nn) * 1024 + d0 + d4] = h;
  }
}

// ---------------- small GEMM (128x128 tile, 4 waves): m' only --------------
// IN=0: bf16 split (hi/lo, 3-MFMA chain). EPI=0: fp32 slab out (split-K).
template<int IN, int EPI>
__global__ __launch_bounds__(256) void gemm_bt(
    const u16* __restrict__ Ah, const u16* __restrict__ Al, int lda,
    const u16* __restrict__ Bh, const u16* __restrict__ Bl, int ldb,
    void* __restrict__ C0, int ldc, int K, size_t zslab){
  constexpr int NPL = 4;
  constexpr int DEPTH = 1;
  constexpr int NBUF = DEPTH + 1;
  __shared__ __align__(16) u16 sm[NBUF * NPL * 4096];

  const int kz = blockIdx.z * K;
  Ah += kz; Bh += kz; Al += kz; Bl += kz;

  const int tid = threadIdx.x;
  const int lane = tid & 63, wave = tid >> 6;
  const int wr = wave >> 1, wc = wave & 1;
  const int lr = lane & 15, kg = lane >> 4;

  const int nwg = gridDim.x * gridDim.y;
  const int id = blockIdx.y * gridDim.x + blockIdx.x;
  const int chunk = nwg >> 3;
  const int swz = (id & 7) * chunk + (id >> 3);
  const int bx = swz % gridDim.x, by = swz / gridDim.x;
  const int m0 = by * 128, n0 = bx * 128;

  const int l_r = lane >> 2, l_c = lane & 3;
  const int st_chunk = l_c ^ ((l_r + (l_r >> 2)) & 3);
  const int rd_swz = (lr + (lr >> 2)) & 3;

  f32x4 acc[4][4];
  #pragma unroll
  for (int m = 0; m < 4; m++)
    #pragma unroll
    for (int n = 0; n < 4; n++)
      acc[m][n] = (f32x4){0.f, 0.f, 0.f, 0.f};

  auto STAGE = [&](int buf, int k0){
    #pragma unroll
    for (int c = 0; c < NPL * 2; ++c){
      int pc = c * 4 + wave;
      int p = pc >> 3, ch = pc & 7;
      const u16* g = (p == 0) ? Ah : (p == 1) ? Al : (p == 2) ? Bh : Bl;
      int ld = (p < 2) ? lda : ldb;
      int rb = (p < 2) ? m0 : n0;
      int r = ch * 16 + l_r;
      const u16* src = g + (size_t)(rb + r) * ld + k0 + st_chunk * 8;
      u16* dst = &sm[((size_t)buf * NPL + p) * 4096 + ch * 512];
      gload16(src, dst);
    }
  };

  const int KT = K >> 5;
  STAGE(0, 0);

  int bufc = 0, pfb = DEPTH % NBUF;
  for (int kt = 0; kt < KT; ++kt){
    const int pf = kt + DEPTH;
    if (pf < KT){
      STAGE(pfb, pf * 32);
      WAITV(8);
    } else {
      WAITV(0);
    }
    __builtin_amdgcn_s_barrier();
    FENCE();

    const u16* pA  = &sm[((size_t)bufc * NPL + 0) * 4096];
    const u16* pAl = &sm[((size_t)bufc * NPL + 1) * 4096];
    const u16* pB  = &sm[((size_t)bufc * NPL + 2) * 4096];
    const u16* pBl = &sm[((size_t)bufc * NPL + 3) * 4096];

    const int slot = (kg ^ rd_swz) * 8;
    bf16x8 afh[4], bfh[4], afl[4], bfl[4];
    #pragma unroll
    for (int m = 0; m < 4; m++){
      int r = wr * 64 + m * 16 + lr;
      afh[m] = *(const bf16x8*)&pA[r * 32 + slot];
      afl[m] = *(const bf16x8*)&pAl[r * 32 + slot];
    }
    #pragma unroll
    for (int n = 0; n < 4; n++){
      int r = wc * 64 + n * 16 + lr;
      bfh[n] = *(const bf16x8*)&pB[r * 32 + slot];
      bfl[n] = *(const bf16x8*)&pBl[r * 32 + slot];
    }
    #pragma unroll
    for (int m = 0; m < 4; m++)
      #pragma unroll
      for (int n = 0; n < 4; n++){
        acc[m][n] = __builtin_amdgcn_mfma_f32_16x16x32_bf16(afh[m], bfh[n], acc[m][n], 0, 0, 0);
        acc[m][n] = __builtin_amdgcn_mfma_f32_16x16x32_bf16(afl[m], bfh[n], acc[m][n], 0, 0, 0);
        acc[m][n] = __builtin_amdgcn_mfma_f32_16x16x32_bf16(afh[m], bfl[n], acc[m][n], 0, 0, 0);
      }
    FENCE();
    __builtin_amdgcn_s_barrier();
    bufc = (bufc + 1 == NBUF) ? 0 : bufc + 1;
    pfb  = (pfb  + 1 == NBUF) ? 0 : pfb  + 1;
  }

  const int row0 = m0 + wr * 64, col0 = n0 + wc * 64 + lr;
  float* C = (float*)C0 + (size_t)blockIdx.z * zslab;
  #pragma unroll
  for (int m = 0; m < 4; m++)
    #pragma unroll
    for (int n = 0; n < 4; n++)
      #pragma unroll
      for (int r = 0; r < 4; r++){
        int row = row0 + m * 16 + kg * 4 + r;
        int col = col0 + n * 16;
        C[(size_t)row * ldc + col] = acc[m][n][r];
      }
}

// ---------------- dual GEMM: t (z@m'^T) || v^T (Wv^T@z^T) in one launch ----
// fp16 in/out, 128x128 tile, 4 waves, DEPTH=2 (triple buffer). Flat grid 512:
// blocks 0-255 -> problem 0 (t, gx=8), 256-511 -> problem 1 (v^T, gx=32).
// 2 blocks/CU co-resident -> m114 MFMA/mem overlap across blocks.
__global__ __launch_bounds__(256) void gemm_dual(
    const u16* __restrict__ A0, int lda0, const u16* __restrict__ B0, int ldb0,
    u16* __restrict__ C0_, int ldc0, int gx0,
    const u16* __restrict__ A1, int lda1, const u16* __restrict__ B1, int ldb1,
    u16* __restrict__ C1_, int ldc1, int gx1, int K){
  constexpr int NPL = 2, DEPTH = 2, NBUF = 3;
  __shared__ __align__(16) u16 sm[NBUF * NPL * 4096];

  const int id = blockIdx.x;
  const int l = id & 255;
  const int swz = (l & 7) * 32 + (l >> 3);          // XCD swizzle in half-grid
  const u16* Ah; const u16* Bh; u16* C; int lda, ldb, ldc, gx;
  if (id < 256){ Ah = A0; Bh = B0; C = C0_; lda = lda0; ldb = ldb0; ldc = ldc0; gx = gx0; }
  else         { Ah = A1; Bh = B1; C = C1_; lda = lda1; ldb = ldb1; ldc = ldc1; gx = gx1; }
  const int bx = swz % gx, by = swz / gx;
  const int m0 = by * 128, n0 = bx * 128;

  const int tid = threadIdx.x;
  const int lane = tid & 63, wave = tid >> 6;
  const int wr = wave >> 1, wc = wave & 1;
  const int lr = lane & 15, kg = lane >> 4;
  const int l_r = lane >> 2, l_c = lane & 3;
  const int st_chunk = l_c ^ ((l_r + (l_r >> 2)) & 3);
  const int rd_swz = (lr + (lr >> 2)) & 3;

  f32x4 acc[4][4];
  #pragma unroll
  for (int m = 0; m < 4; m++)
    #pragma unroll
    for (int n = 0; n < 4; n++)
      acc[m][n] = (f32x4){0.f, 0.f, 0.f, 0.f};

  auto STAGE = [&](int buf, int k0){
    #pragma unroll
    for (int c = 0; c < NPL * 2; ++c){
      int pc = c * 4 + wave;
      int p = pc >> 3, ch = pc & 7;
      const u16* g = (p == 0) ? Ah : Bh;
      int ld = (p == 0) ? lda : ldb;
      int rb = (p == 0) ? m0 : n0;
      int r = ch * 16 + l_r;
      const u16* src = g + (size_t)(rb + r) * ld + k0 + st_chunk * 8;
      u16* dst = &sm[((size_t)buf * NPL + p) * 4096 + ch * 512];
      gload16(src, dst);
    }
  };

  const int KT = K >> 5;
  STAGE(0, 0);
  if (KT > 1) STAGE(1, 32);

  int bufc = 0, pfb = DEPTH % NBUF;
  for (int kt = 0; kt < KT; ++kt){
    const int pf = kt + DEPTH;
    if (pf < KT){
      STAGE(pfb, pf * 32);
      WAITV(8);
    } else if (kt + 1 < KT){
      WAITV(4);
    } else {
      WAITV(0);
    }
    __builtin_amdgcn_s_barrier();
    FENCE();

    const u16* pA = &sm[((size_t)bufc * NPL + 0) * 4096];
    const u16* pB = &sm[((size_t)bufc * NPL + 1) * 4096];

    const int slot = (kg ^ rd_swz) * 8;
    f16x8 ah[4], bh[4];
    #pragma unroll
    for (int m = 0; m < 4; m++){
      int r = wr * 64 + m * 16 + lr;
      ah[m] = *(const f16x8*)&pA[r * 32 + slot];
    }
    #pragma unroll
    for (int n = 0; n < 4; n++){
      int r = wc * 64 + n * 16 + lr;
      bh[n] = *(const f16x8*)&pB[r * 32 + slot];
    }
    #pragma unroll
    for (int m = 0; m < 4; m++)
      #pragma unroll
      for (int n = 0; n < 4; n++)
        acc[m][n] = __builtin_amdgcn_mfma_f32_16x16x32_f16(ah[m], bh[n], acc[m][n], 0, 0, 0);
    FENCE();
    __builtin_amdgcn_s_barrier();
    bufc = (bufc + 1 == NBUF) ? 0 : bufc + 1;
    pfb  = (pfb  + 1 == NBUF) ? 0 : pfb  + 1;
  }

  const int row0 = m0 + wr * 64, col0 = n0 + wc * 64 + lr;
  #pragma unroll
  for (int m = 0; m < 4; m++)
    #pragma unroll
    for (int n = 0; n < 4; n++)
      #pragma unroll
      for (int r = 0; r < 4; r++){
        int row = row0 + m * 16 + kg * 4 + r;
        int col = col0 + n * 16;
        C[(size_t)row * ldc + col] = f2h(acc[m][n][r]);
      }
}

// ---------------- big GEMM: 256x256 tile, BK=64, 8 waves, wave 128x64 ------
// fp16 in. EPI 0 = fp32 out; 1 = fp16 out. (R11 schedule: best measured
// across 6 structural variants; 2-phase, 1 barrier + 1 vmcnt per K-tile.)
// LDS 128KB = 2 bufs x (A 32KB + B 32KB). 8-slot XOR involution swizzle,
// zero bank conflicts (verified R11).
template<int EPI>
__global__ __launch_bounds__(512, 1) void gemm256(
    const u16* __restrict__ A, int lda,
    const u16* __restrict__ B, int ldb,
    void* __restrict__ C0z, int l0, void* __restrict__ C1z, int l1,
    void* __restrict__ C2z, int l2, void* __restrict__ C3z, int l3,
    int K){
  __shared__ __align__(16) u16 sm[2 * 32768];

  const int tid = threadIdx.x;
  const int lane = tid & 63, wave = tid >> 6;
  const int wr = wave >> 2, wc = wave & 3;        // 2 x 4 waves
  const int lr = lane & 15, kg = lane >> 4;
  const int g7 = lr & 7;

  const int nwg = gridDim.x * gridDim.y;
  const int id = blockIdx.y * gridDim.x + blockIdx.x;
  const int chunk = nwg >> 3;
  const int swz = (id & 7) * chunk + (id >> 3);
  const int bx = swz % gridDim.x, by = swz / gridDim.x;
  const int m0 = by * 256, n0 = bx * 256;

  A += (size_t)blockIdx.z * (size_t)K;
  B += (size_t)blockIdx.z * (size_t)K;
  void* Cp; int ldc;
  if (blockIdx.z == 0){ Cp = C0z; ldc = l0; }
  else if (blockIdx.z == 1){ Cp = C1z; ldc = l1; }
  else if (blockIdx.z == 2){ Cp = C2z; ldc = l2; }
  else { Cp = C3z; ldc = l3; }

  auto STAGE = [&](int buf, int k0){
    #pragma unroll
    for (int rd = 0; rd < 8; ++rd){
      int p = rd >> 2;
      int r0 = (rd & 3) * 64 + wave * 8;
      const u16* g = p ? B : A;
      int ld = p ? ldb : lda;
      int rb = p ? n0 : m0;
      int grow = rb + r0 + (lane >> 3);
      int gch = (lane & 7) ^ (lane >> 3);
      const u16* src = g + (size_t)grow * ld + k0 + gch * 8;
      u16* dst = &sm[(size_t)buf * 32768 + p * 16384 + r0 * 64];
      gload16(src, dst);
    }
  };

  f32x4 acc[8][4];
  #pragma unroll
  for (int m = 0; m < 8; m++)
    #pragma unroll
    for (int n = 0; n < 4; n++)
      acc[m][n] = (f32x4){0.f, 0.f, 0.f, 0.f};

  const int KT = K >> 6;
  STAGE(0, 0);

  int bufc = 0;
  for (int kt = 0; kt < KT; ++kt){
    WAITV(0);
    __builtin_amdgcn_s_barrier();
    FENCE();
    if (kt + 1 < KT) STAGE(bufc ^ 1, (kt + 1) * 64);

    const u16* pA = &sm[(size_t)bufc * 32768];
    const u16* pB = pA + 16384;
    #pragma unroll
    for (int ks = 0; ks < 2; ++ks){
      f16x8 b[4], a[8];
      #pragma unroll
      for (int n = 0; n < 4; n++){
        int R = wc * 64 + n * 16 + lr;
        b[n] = *(const f16x8*)&pB[R * 64 + (((ks * 4 + kg) ^ g7) * 8)];
      }
      #pragma unroll
      for (int m = 0; m < 8; m++){
        int R = wr * 128 + m * 16 + lr;
        a[m] = *(const f16x8*)&pA[R * 64 + (((ks * 4 + kg) ^ g7) * 8)];
      }
      __builtin_amdgcn_s_setprio(1);
      #pragma unroll
      for (int m = 0; m < 8; m++)
        #pragma unroll
        for (int n = 0; n < 4; n++)
          acc[m][n] = __builtin_amdgcn_mfma_f32_16x16x32_f16(a[m], b[n], acc[m][n], 0, 0, 0);
      __builtin_amdgcn_s_setprio(0);
    }
    FENCE();
    bufc ^= 1;
  }

  const int row0 = m0 + wr * 128, col0 = n0 + wc * 64 + lr;
  #pragma unroll
  for (int m = 0; m < 8; m++)
    #pragma unroll
    for (int n = 0; n < 4; n++)
      #pragma unroll
      for (int r = 0; r < 4; r++){
        int row = row0 + m * 16 + kg * 4 + r;
        int col = col0 + n * 16;
        if (EPI == 0) ((float*)Cp)[(size_t)row * ldc + col] = acc[m][n][r];
        else          ((u16*)Cp)[(size_t)row * ldc + col] = f2h(acc[m][n][r]);
      }
}

// ---------------- reduce: dst16 = fp16(s0+s1+s2+s3) ----------------
__global__ __launch_bounds__(256) void reduce_t(u16* __restrict__ dst,
                                                const float* __restrict__ s0,
                                                const float* __restrict__ s1,
                                                const float* __restrict__ s2,
                                                const float* __restrict__ s3){
  int idx = blockIdx.x * 256 + threadIdx.x;
  float4 a = ((const float4*)s0)[idx];
  float4 b = ((const float4*)s1)[idx];
  float4 c = ((const float4*)s2)[idx];
  float4 d = ((const float4*)s3)[idx];
  ushort4 o;
  o.x = f2h((a.x + b.x) + (c.x + d.x));
  o.y = f2h((a.y + b.y) + (c.y + d.y));
  o.z = f2h((a.z + b.z) + (c.z + d.z));
  o.w = f2h((a.w + b.w) + (c.w + d.w));
  ((ushort4*)dst)[idx] = o;
}

// ---------------- reduce: out += s1 + s2 + s3 (flat fp32 slabs) ------------
__global__ __launch_bounds__(256) void reduce_pv4(float* __restrict__ out,
                                                  const float* __restrict__ s1,
                                                  const float* __restrict__ s2,
                                                  const float* __restrict__ s3){
  int idx = blockIdx.x * 256 + threadIdx.x;
  float4 a = ((const float4*)out)[idx];
  float4 b = ((const float4*)s1)[idx];
  float4 c = ((const float4*)s2)[idx];
  float4 d = ((const float4*)s3)[idx];
  float4 o;
  o.x = (a.x + b.x) + (c.x + d.x);
  o.y = (a.y + b.y) + (c.y + d.y);
  o.z = (a.z + b.z) + (c.z + d.z);
  o.w = (a.w + b.w) + (c.w + d.w);
  ((float4*)out)[idx] = o;
}

// ---------------- softmax over fp16 S rows (4096), write P fp16 in place ---
__global__ __launch_bounds__(256) void softmax16(u16* __restrict__ S){
  int row = blockIdx.x;
  _Float16* srow = (_Float16*)(S + (size_t)row * 4096);
  __shared__ float e[4096];
  __shared__ float red[4];
  int tid = threadIdx.x;

  float m = -1e30f;
  for (int i = tid * 8; i < 4096; i += 2048){
    f16x8 v = *(const f16x8*)(srow + i);
    #pragma unroll
    for (int j = 0; j < 8; j++) m = fmaxf(m, (float)v[j]);
  }
  for (int o = 32; o > 0; o >>= 1) m = fmaxf(m, __shfl_xor(m, o));
  if ((tid & 63) == 0) red[tid >> 6] = m;
  __syncthreads();
  m = fmaxf(fmaxf(red[0], red[1]), fmaxf(red[2], red[3]));

  float s = 0.f;
  for (int i = tid * 8; i < 4096; i += 2048){
    f16x8 v = *(const f16x8*)(srow + i);
    #pragma unroll
    for (int j = 0; j < 8; j++){
      float ev = __expf((float)v[j] - m);
      s += ev;
      e[i + j] = ev;
    }
  }
  for (int o = 32; o > 0; o >>= 1) s += __shfl_xor(s, o);
  __syncthreads();
  if ((tid & 63) == 0) red[tid >> 6] = s;
  __syncthreads();
  s = (red[0] + red[1]) + (red[2] + red[3]);

  float scale = 0.03125f / s;    // fold post-softmax 1/sqrt(dk)=1/32 into P
  for (int i = tid * 8; i < 4096; i += 2048){
    f16x8 o;
    #pragma unroll
    for (int j = 0; j < 8; j++) o[j] = (_Float16)(e[i + j] * scale);
    *(f16x8*)(srow + i) = o;
  }
}

extern "C" void kernel_launch(void* const* d_in, const int* in_sizes, int n_in,
                              void* d_out, int out_size, void* d_ws, size_t ws_size,
                              hipStream_t stream){
  const float* z  = (const float*)d_in[0];
  const float* Wq = (const float*)d_in[1];
  const float* Wk = (const float*)d_in[2];
  const float* Wv = (const float*)d_in[3];
  char* ws = (char*)d_ws;
  const size_t MB = 1ull << 20;

  // layout: 0-8 t16 | 8-16 z16 | 16-24 vt16 | 24-56 S/P fp16 | 56-88 PV slabs
  //         88-90 m16. prep scratch 24-56 (dead before S written).
  u16* t16   = (u16*)(ws + 0 * MB);
  u16* z16   = (u16*)(ws + 8 * MB);
  u16* vt16  = (u16*)(ws + 16 * MB);
  u16* S16   = (u16*)(ws + 24 * MB);              // fp16 [4096][4096]
  u16* m16   = (u16*)(ws + 88 * MB);
  float* pv1 = (float*)(ws + 56 * MB);            // PV partial slabs
  float* pv2 = (float*)(ws + 72 * MB);
  float* pv3 = (float*)(ws + 0 * MB);             // t16/z16 dead after S
  // prep scratch (24-56, dead before S):
  u16* wqh   = (u16*)(ws + 24 * MB);
  u16* wql   = (u16*)(ws + 26 * MB);
  u16* wkh   = (u16*)(ws + 28 * MB);
  u16* wkl   = (u16*)(ws + 30 * MB);
  u16* wvt16 = (u16*)(ws + 32 * MB);
  float* msl = (float*)(ws + 40 * MB);            // m' slabs 4x4MB (40-56)

  conv_h16<<<4096, 256, 0, stream>>>(z, z16, 4096 * 1024 / 4);
  split_wqk<<<2048, 256, 0, stream>>>(Wq, Wk, wqh, wql, wkh, wkl);
  transpose_wv16<<<dim3(16, 16), 256, 0, stream>>>(Wv, wvt16);

  // m'[m,n] = sum_a Wk[m,a] Wq[n,a]  (split, split-K=4 -> fp32 slabs)
  gemm_bt<0, 0><<<dim3(8, 8, 4), 256, 0, stream>>>(wkh, wkl, 1024,
      wqh, wql, 1024, msl, 1024, 256, (size_t)1024 * 1024);
  reduce_t<<<1024, 256, 0, stream>>>(m16, msl, msl + 1048576,
      msl + 2097152, msl + 3145728);

  // t = z16 @ m16^T  ||  v^T = Wv^T @ z^T   (one 512-block launch)
  gemm_dual<<<512, 256, 0, stream>>>(
      z16, 1024, m16, 1024, t16, 1024, 8,
      wvt16, 1024, z16, 1024, vt16, 4096, 32, 1024);

  // S = t16 @ z16^T  fp16 out  M=N=4096 K=1024
  gemm256<1><<<dim3(16, 16, 1), 512, 0, stream>>>(t16, 1024, z16, 1024,
      S16, 4096, S16, 4096, S16, 4096, S16, 4096, 1024);

  // softmax rows (fp16 in/out, in place), 1/32 folded in
  softmax16<<<4096, 256, 0, stream>>>(S16);

  // out = P @ v, split-K=4: z0 -> d_out, z1-3 -> flat fp32 slabs
  gemm256<0><<<dim3(4, 16, 4), 512, 0, stream>>>(S16, 4096, vt16, 4096,
      (float*)d_out, 1024, pv1, 1024, pv2, 1024, pv3, 1024, 1024);

  // out += pv1 + pv2 + pv3
  reduce_pv4<<<4096, 256, 0, stream>>>((float*)d_out, pv1, pv2, pv3);
}